// Round 14
// baseline (806.774 us; speedup 1.0000x reference)
//
#include <hip/hip_runtime.h>

#define N_NODES 50000
#define N_EDGES 800000
#define D 128
#define NB2 782     // ceil(50000/64) buckets of 64 nodes (dst>>6)
#define CAP2 1300   // per-bucket capacity; mean 1024, sigma ~32 -> 8.6 sigma
#define CHUNK 4096  // edges per passA block (16/thread)
#define PA_BLKS ((N_EDGES + CHUNK - 1) / CHUNK)  // 196
#define FB_BLKS 12500                            // N_NODES*64/256
#define WT_BLKS 64                               // 16384/256

typedef __attribute__((ext_vector_type(8))) short short8;
typedef __attribute__((ext_vector_type(4))) float f32x4;

__device__ __forceinline__ unsigned short f2bf(float f) {
    unsigned u = __float_as_uint(f);
    u += 0x7fff + ((u >> 16) & 1);  // RNE
    return (unsigned short)(u >> 16);
}
__device__ __forceinline__ float lo16f(unsigned u) { return __uint_as_float(u << 16); }
__device__ __forceinline__ float hi16f(unsigned u) { return __uint_as_float(u & 0xffff0000u); }

// ---------------------------------------------------------------------------
// K1 (fused): passA buckets edges by dst>>6 into tmp (16 edges/thread, packed
// key = src | dlocal<<16 | bucket<<22); prep converts feature -> packed-bf16
// fb (fb[n*64+i] = {col i, col i+64} -- conflict-free LDS-accumulate layout)
// and W -> bf16 n-major Wt. gcur pre-zeroed via memsetAsync.
// ---------------------------------------------------------------------------
__global__ __launch_bounds__(256) void prep_passA(
    const float* __restrict__ feat, unsigned* __restrict__ fb,
    const float* __restrict__ W, unsigned short* __restrict__ Wt,
    const int* __restrict__ esrc, const int* __restrict__ edst,
    const float* __restrict__ ew, int* __restrict__ gcur,
    uint2* __restrict__ tmp) {
    __shared__ int lh[NB2], lbase[NB2], lcur[NB2];
    int blk = blockIdx.x, t = threadIdx.x;

    if (blk >= PA_BLKS) {
        int b2 = blk - PA_BLKS;
        if (b2 < FB_BLKS) {
            int i = b2 * 256 + t;               // u32 index: n = i>>6, pos = i&63
            int n = i >> 6, pos = i & 63;
            unsigned lo = f2bf(feat[(size_t)n * D + pos]);
            unsigned hi = f2bf(feat[(size_t)n * D + pos + 64]);
            fb[i] = lo | (hi << 16);
        } else {
            int idx = (b2 - FB_BLKS) * 256 + t;  // 16384 weight elements
            int n = idx >> 7, k = idx & 127;
            Wt[idx] = f2bf(W[k * 128 + n]);
        }
        return;
    }

    // ---- passA ----
    for (int i = t; i < NB2; i += 256) lh[i] = 0;
    __syncthreads();
    int e0 = blk * CHUNK;
    unsigned key[16];
    float wv[16];
#pragma unroll
    for (int j = 0; j < 16; ++j) {
        int e = e0 + j * 256 + t;
        if (e < N_EDGES) {
            int src = esrc[e], dd = edst[e];
            key[j] = (unsigned)src | ((unsigned)(dd & 63) << 16) |
                     ((unsigned)(dd >> 6) << 22);
            wv[j] = ew[e];
            atomicAdd(&lh[dd >> 6], 1);
        } else key[j] = 0xffc00000u;  // invalid bucket marker (1023)
    }
    __syncthreads();
    for (int i = t; i < NB2; i += 256) {
        lbase[i] = atomicAdd(&gcur[i], lh[i]);
        lcur[i] = 0;
    }
    __syncthreads();
#pragma unroll
    for (int j = 0; j < 16; ++j) {
        int b = key[j] >> 22;
        if (b < NB2) {
            int r = atomicAdd(&lcur[b], 1);
            tmp[(size_t)b * CAP2 + lbase[b] + r] =
                make_uint2(key[j] & 0x003fffffu, __float_as_uint(wv[j]));
        }
    }
}

// ---------------------------------------------------------------------------
// K2 (fused): block = one bucket of 64 nodes. LDS fp32 accumulator
// acc[64][128] (32 KB -> 4 blocks/CU = 16 waves/CU). Waves split the
// bucket's ~1024 edges; 16-deep gather batches (R5-best structure);
// accumulate via LDS atomicAdd at acc[dl][lane]/acc[dl][lane+64]
// (2 lanes/bank, conflict-free). Eliminates passB/sw/offsets entirely.
// tmp now lives in the WORKSPACE (R12's d_out alias raced with the epilogue
// stores -- blocks read tmp while other blocks wrote out; absmax 3.87).
// Blend 0.5*(acc+feat), then 4 waves do 4x (16x128 @ 128x128) MFMA.
// mfma_f32_16x16x32_bf16: A[m=lane&15][k=quad*8+j], B[k][n=lane&15],
// D row=quad*4+reg, col=lane&15 (verified; R2-R11 passed).
// ---------------------------------------------------------------------------
__global__ __launch_bounds__(256) void agg_gemm(const int* __restrict__ gcur,
                                                const uint2* __restrict__ tmp,
                                                const unsigned* __restrict__ fb,
                                                const unsigned short* __restrict__ Wt,
                                                float* __restrict__ out) {
    __shared__ float acc[64][128];  // 32 KiB
    int b = blockIdx.x, t = threadIdx.x;
    int wave = t >> 6, lane = t & 63;

    // zero the accumulator
    {
        float4* a4 = (float4*)&acc[0][0];
#pragma unroll
        for (int k = 0; k < 8; ++k) a4[t + k * 256] = make_float4(0.f, 0.f, 0.f, 0.f);
    }
    __syncthreads();

    int cnt = gcur[b];
    const uint2* seg = tmp + (size_t)b * CAP2;
    int chunk = (cnt + 3) >> 2;
    int e0 = wave * chunk;
    int e1 = min(cnt, e0 + chunk);

#pragma unroll 1
    for (int e = e0; e < e1; e += 16) {
        int rem = e1 - e;  // >= 1
        uint2 p[16];
        unsigned u[16];
#pragma unroll
        for (int j = 0; j < 16; ++j) {
            int idx = (j < rem) ? j : rem - 1;
            p[j] = seg[e + idx];            // wave-uniform -> scalar loads
            if (j >= rem) p[j].y = 0u;      // pad edges contribute w=0
        }
#pragma unroll
        for (int j = 0; j < 16; ++j)
            u[j] = fb[(size_t)(p[j].x & 0xffffu) * 64 + lane];
#pragma unroll
        for (int j = 0; j < 16; ++j) {
            float w = __uint_as_float(p[j].y);
            int dl = p[j].x >> 16;          // 0..63
            atomicAdd(&acc[dl][lane], w * lo16f(u[j]));
            atomicAdd(&acc[dl][lane + 64], w * hi16f(u[j]));
        }
    }
    __syncthreads();

    // blend: acc = 0.5*(acc + feature); wave owns rows [wave*16, wave*16+16)
    for (int r = wave * 16; r < wave * 16 + 16; ++r) {
        int n = b * 64 + r;
        if (n >= N_NODES) break;
        unsigned u = fb[(size_t)n * 64 + lane];
        acc[r][lane]      = 0.5f * (acc[r][lane]      + lo16f(u));
        acc[r][lane + 64] = 0.5f * (acc[r][lane + 64] + hi16f(u));
    }
    __syncthreads();

    // MFMA epilogue: wave w handles row-tile w (rows w*16..w*16+15)
    int quad = lane >> 4;
    int col  = lane & 15;
    int m = wave * 16 + col;
    short8 a[4];
#pragma unroll
    for (int kk = 0; kk < 4; ++kk) {
        const float* ap = &acc[m][kk * 32 + quad * 8];
        float4 lo = *reinterpret_cast<const float4*>(ap);
        float4 hi = *reinterpret_cast<const float4*>(ap + 4);
        short8 av;
        av[0] = (short)f2bf(lo.x); av[1] = (short)f2bf(lo.y);
        av[2] = (short)f2bf(lo.z); av[3] = (short)f2bf(lo.w);
        av[4] = (short)f2bf(hi.x); av[5] = (short)f2bf(hi.y);
        av[6] = (short)f2bf(hi.z); av[7] = (short)f2bf(hi.w);
        a[kk] = av;
    }
    int grow0 = b * 64 + wave * 16;
#pragma unroll
    for (int n0 = 0; n0 < 8; ++n0) {
        const short8* bp = reinterpret_cast<const short8*>(Wt) + ((n0 * 16 + col) * 16 + quad);
        f32x4 c = {0.f, 0.f, 0.f, 0.f};
        c = __builtin_amdgcn_mfma_f32_16x16x32_bf16(a[0], bp[0],  c, 0, 0, 0);
        c = __builtin_amdgcn_mfma_f32_16x16x32_bf16(a[1], bp[4],  c, 0, 0, 0);
        c = __builtin_amdgcn_mfma_f32_16x16x32_bf16(a[2], bp[8],  c, 0, 0, 0);
        c = __builtin_amdgcn_mfma_f32_16x16x32_bf16(a[3], bp[12], c, 0, 0, 0);
#pragma unroll
        for (int rr = 0; rr < 4; ++rr) {
            int gr = grow0 + quad * 4 + rr;
            if (gr < N_NODES) out[(size_t)gr * D + n0 * 16 + col] = c[rr];
        }
    }
}

// ---------------------------------------------------------------------------
extern "C" void kernel_launch(void* const* d_in, const int* in_sizes, int n_in,
                              void* d_out, int out_size, void* d_ws, size_t ws_size,
                              hipStream_t stream) {
    const float* feat = (const float*)d_in[0];
    const int*   esrc = (const int*)d_in[1];
    const int*   edst = (const int*)d_in[2];
    const float* ew   = (const float*)d_in[3];
    const float* W    = (const float*)d_in[4];
    float*       out  = (float*)d_out;

    // Workspace (256 MiB per R4 fill counters); 21.0 MB used, no d_out alias.
    char* ws = (char*)d_ws;
    unsigned*       fb   = (unsigned*)(ws + 0);               // 12,800,000
    unsigned short* Wt   = (unsigned short*)(ws + 12800000);  //     32,768
    int*            gcur = (int*)(ws + 12832768);             //      3,128
    uint2*          tmp  = (uint2*)(ws + 12835904);           //  8,132,800

    hipMemsetAsync(gcur, 0, NB2 * sizeof(int), stream);
    prep_passA<<<PA_BLKS + FB_BLKS + WT_BLKS, 256, 0, stream>>>(
        feat, fb, W, Wt, esrc, edst, ew, gcur, tmp);
    agg_gemm<<<NB2, 256, 0, stream>>>(gcur, tmp, fb, Wt, out);
}